// Round 1
// baseline (787.174 us; speedup 1.0000x reference)
//
#include <hip/hip_runtime.h>
#include <cfloat>

// VQ-VAE vector quantizer. Round 6: convert k_argmin_mfma's K-loop from the
// 0-phase (stage -> drain -> compute) schedule to a double-buffered 2-phase
// pipeline (T3-minimum recipe): stage tile k+1 while computing tile k, one
// barrier per BK=32 step. Same instruction counts per virtual-K as round 5;
// only ordering changes. Separate __shared__ arrays per buffer so alias
// analysis doesn't force a vmcnt drain between stage(buf^1) and ds_read(buf).
// N=32768 rows, K=8192 codes, D=256.
#define K_CODES 8192
#define DIM     256
#define NROWS   32768

// d_out float offsets (outputs concatenated in reference return order)
#define O_ZQ    0
#define O_LOSS  8388608
#define O_IDX   8388609
#define O_NEMB  8421377
#define O_NCS   10518529
#define O_NEMAW 10526721

// ---- MFMA path params
#define NCH          2                    // code chunks
#define CODES_PER_CH (K_CODES / NCH)      // 4096
#define NT_TILES     (CODES_PER_CH / 256) // 16

typedef __attribute__((ext_vector_type(8))) short short8;
typedef __attribute__((ext_vector_type(4))) float floatx4;

__device__ __forceinline__ unsigned short f2bf_rne(float x) {
    unsigned u = __float_as_uint(x);
    u += 0x7fffu + ((u >> 16) & 1u);
    return (unsigned short)(u >> 16);
}
__device__ __forceinline__ float bf2f(unsigned short h) {
    return __uint_as_float(((unsigned)h) << 16);
}
__device__ __forceinline__ void async16(const void* g, void* l) {
    __builtin_amdgcn_global_load_lds(
        (const __attribute__((address_space(1))) void*)g,
        (__attribute__((address_space(3))) void*)l, 16, 0, 0);
}

// ---------------------------------------------------------------- fused convert: z & emb -> {hi,lo} bf16 + |e|^2 + zero
__global__ void k_prep(const float* __restrict__ z, const float* __restrict__ emb,
                       unsigned short* __restrict__ zcat, unsigned short* __restrict__ ecat,
                       float* __restrict__ esq, int* __restrict__ zero16k) {
    const int b = blockIdx.x;
    if (b < 8192) {
        const int i = b * 256 + threadIdx.x;         // float4 idx, 2,097,152
        const int row = i >> 6;
        const int col = (i & 63) << 2;
        float4 v = ((const float4*)z)[i];
        // fold -2 into z: bf16(-2z) == -2*bf16(z) exactly (pow2 scale)
        float nx = -2.0f * v.x, ny = -2.0f * v.y, nz = -2.0f * v.z, nw = -2.0f * v.w;
        ushort4 h, l;
        h.x = f2bf_rne(nx); l.x = f2bf_rne(nx - bf2f(h.x));
        h.y = f2bf_rne(ny); l.y = f2bf_rne(ny - bf2f(h.y));
        h.z = f2bf_rne(nz); l.z = f2bf_rne(nz - bf2f(h.z));
        h.w = f2bf_rne(nw); l.w = f2bf_rne(nw - bf2f(h.w));
        *(ushort4*)&zcat[(size_t)row * 512 + col]       = h;
        *(ushort4*)&zcat[(size_t)row * 512 + 256 + col] = l;
    } else {
        const int gid  = (b - 8192) * 256 + threadIdx.x;  // 0..524287
        if (gid < 2 * K_CODES) zero16k[gid] = 0;          // counts + cursor
        const int code = gid >> 6;
        const int lane = gid & 63;
        const int col  = lane << 2;
        float4 v = ((const float4*)emb)[code * 64 + lane];
        ushort4 h, l;
        h.x = f2bf_rne(v.x); l.x = f2bf_rne(v.x - bf2f(h.x));
        h.y = f2bf_rne(v.y); l.y = f2bf_rne(v.y - bf2f(h.y));
        h.z = f2bf_rne(v.z); l.z = f2bf_rne(v.z - bf2f(h.z));
        h.w = f2bf_rne(v.w); l.w = f2bf_rne(v.w - bf2f(h.w));
        *(ushort4*)&ecat[(size_t)code * 512 + col]       = h;
        *(ushort4*)&ecat[(size_t)code * 512 + 256 + col] = l;
        float s = fmaf(v.x, v.x, fmaf(v.y, v.y, fmaf(v.z, v.z, v.w * v.w)));
#pragma unroll
        for (int off = 32; off > 0; off >>= 1) s += __shfl_down(s, off, 64);
        if (lane == 0) esq[code] = s;
    }
}

// ---------------------------------------------------------------- MFMA argmin GEMM (virtual K=768, BK=32, 128x256 tile)
// score(n,k) = esq[k] + dot(zcat_n, ecat_k segs), zcat encodes -2z.
// A segs {hi,hi,lo}: off_a=(k0&255)|((k0&512)>>1); B segs {hi,lo,hi}: off_b=k0&511.
// 2-phase double-buffered pipeline: stage step s+1 (global_load_lds into
// buf^1) is issued BEFORE compute of step s (ds_read from buf); the single
// __syncthreads() per step drains the prefetch after it hid under 32 MFMAs.
// LDS layout (BK=32, 64B rows of 4x16B chunks): logical chunk c of row R at
// physical chunk c ^ ((R>>1)&3). Per aligned 8-lane phase group the b128
// reads cover 8 distinct 16B slots (even m -> banks 0-15, odd m -> 16-31):
// conflict-free. Stage pre-swizzles the GLOBAL source (linear LDS dest).
// 4 waves, wave-tile 64x128: wrow=(w>>1)*64, wcol=(w&1)*128, acc 4x8 of 16x16x32.
#define STAGE(AS, BS, ntv, offa, offb)                                          \
    do {                                                                        \
        _Pragma("unroll")                                                       \
        for (int c_ = 0; c_ < 6; ++c_) {                                        \
            const int u_ = w * 6 + c_;                                          \
            if (u_ < 8)                                                         \
                async16(aGlob + (size_t)u_ * 8192 + (offa), &AS[u_ * 512]);     \
            else                                                                \
                async16(bGlob + (size_t)(ntv) * 131072 +                        \
                            (size_t)(u_ - 8) * 8192 + (offb),                   \
                        &BS[(u_ - 8) * 512]);                                   \
        }                                                                       \
    } while (0)

#define COMPUTE(AS, BS)                                                         \
    do {                                                                        \
        short8 af_[4], bf_[8];                                                  \
        _Pragma("unroll")                                                       \
        for (int i_ = 0; i_ < 4; ++i_)                                          \
            af_[i_] = *(const short8*)&AS[(wrow + i_ * 16 + m) * 32 + xo];      \
        _Pragma("unroll")                                                       \
        for (int j_ = 0; j_ < 8; ++j_)                                          \
            bf_[j_] = *(const short8*)&BS[(wcol + j_ * 16 + m) * 32 + xo];      \
        _Pragma("unroll")                                                       \
        for (int i_ = 0; i_ < 4; ++i_)                                          \
            _Pragma("unroll")                                                   \
            for (int j_ = 0; j_ < 8; ++j_)                                      \
                acc[i_][j_] = __builtin_amdgcn_mfma_f32_16x16x32_bf16(          \
                    af_[i_], bf_[j_], acc[i_][j_], 0, 0, 0);                    \
    } while (0)

__global__ __launch_bounds__(256, 2) void k_argmin_mfma(
        const unsigned short* __restrict__ zcat, const unsigned short* __restrict__ ecat,
        const float* __restrict__ esq,
        float* __restrict__ part_v, int* __restrict__ part_i) {
    // double buffer as SEPARATE arrays (alias analysis keeps stage/compute
    // independent). A: 128x32 ushort = 8 KB each; B: 256x32 = 16 KB each.
    __shared__ __align__(16) unsigned short a0_s[128 * 32];
    __shared__ __align__(16) unsigned short a1_s[128 * 32];
    __shared__ __align__(16) unsigned short b0_s[256 * 32];
    __shared__ __align__(16) unsigned short b1_s[256 * 32];
    const int t    = threadIdx.x;
    const int w    = t >> 6;
    const int lane = t & 63;
    const int quad = lane >> 4;
    const int m    = lane & 15;
    const int wrow = (w >> 1) * 64;
    const int wcol = (w & 1) * 128;
    const int row0   = blockIdx.x * 128;
    const int cbase0 = blockIdx.y * CODES_PER_CH;

    // staging geometry: 1536 16B slots/step (512 A + 1024 B) = 24 wave-chunks
    // of 64 slots; wave w takes u = w*6..w*6+5 (u<8 -> A rows u*16.., else B
    // rows (u-8)*16..). Lane covers slot (prow=lane>>2, pchunk=lane&3) which
    // holds logical chunk (lane&3) ^ ((lane>>3)&3) of its row.
    const int    swz    = (((lane & 3) ^ ((lane >> 3) & 3)) << 3);  // ushorts
    const size_t srcrow = (size_t)(lane >> 2) * 512 + swz;
    const unsigned short* aGlob = zcat + (size_t)row0 * 512 + srcrow;
    const unsigned short* bGlob = ecat + (size_t)cbase0 * 512 + srcrow;

    // fragment-read swizzle: physical chunk = quad ^ ((m>>1)&3), kk-invariant
    const int xo = ((quad ^ ((m >> 1) & 3)) << 3);

    float    best_v[16];
    unsigned best_p[4];     // per i: 4 reg-slots x 8-bit candidate (nt*8+j)
#pragma unroll
    for (int r = 0; r < 16; ++r) best_v[r] = FLT_MAX;
#pragma unroll
    for (int i = 0; i < 4; ++i) best_p[i] = 0u;

    // prologue: stage (nt=0, k0=0) into buf0; load esq for nt=0
    STAGE(a0_s, b0_s, 0, 0, 0);
    float es[8];
#pragma unroll
    for (int j = 0; j < 8; ++j) es[j] = esq[cbase0 + wcol + j * 16 + m];
    __syncthreads();   // drains prologue stage (vmcnt 0 at barrier)

    for (int nt = 0; nt < NT_TILES; ++nt) {
        floatx4 acc[4][8];
#pragma unroll
        for (int j = 0; j < 8; ++j) {
            const float e = es[j];
#pragma unroll
            for (int i = 0; i < 4; ++i) acc[i][j] = (floatx4){e, e, e, e};
        }

        for (int kk2 = 0; kk2 < 12; ++kk2) {
            {   // step A: stage k0=64*kk2+32 into buf1, compute 64*kk2 from buf0
                const int nk0 = kk2 * 64 + 32;
                STAGE(a1_s, b1_s, nt, (nk0 & 255) | ((nk0 & 512) >> 1), nk0 & 511);
                COMPUTE(a0_s, b0_s);
                __syncthreads();
            }
            {   // step B: stage next step into buf0, compute from buf1
                if (kk2 < 11) {
                    const int nk0 = kk2 * 64 + 64;
                    STAGE(a0_s, b0_s, nt, (nk0 & 255) | ((nk0 & 512) >> 1), nk0 & 511);
                } else if (nt + 1 < NT_TILES) {
                    STAGE(a0_s, b0_s, nt + 1, 0, 0);    // first step of next nt
                }
                if (kk2 == 10 && nt + 1 < NT_TILES) {   // esq prefetch, next nt
#pragma unroll
                    for (int j = 0; j < 8; ++j)
                        es[j] = esq[cbase0 + (nt + 1) * 256 + wcol + j * 16 + m];
                }
                COMPUTE(a1_s, b1_s);
                __syncthreads();
            }
        }
        // epilogue: acc IS the score. codes ascend in (nt,j): strict < = first-min.
#pragma unroll
        for (int j = 0; j < 8; ++j) {
            const unsigned cand = (unsigned)(nt * 8 + j);   // 7 bits
#pragma unroll
            for (int i = 0; i < 4; ++i)
#pragma unroll
                for (int reg = 0; reg < 4; ++reg) {
                    const float s = acc[i][j][reg];
                    const int r = i * 4 + reg;
                    if (s < best_v[r]) {
                        best_v[r] = s;
                        best_p[i] = (best_p[i] & ~(255u << (reg * 8))) | (cand << (reg * 8));
                    }
                }
        }
    }
    // reconstruct codes, butterfly across the 16 lanes sharing each row
    __syncthreads();               // staging LDS free for reuse
    float* redv = (float*)a0_s;    // [128][2]
    int*   redi = (int*)b0_s;      // [128][2]
#pragma unroll
    for (int i = 0; i < 4; ++i)
#pragma unroll
        for (int reg = 0; reg < 4; ++reg) {
            const int r = i * 4 + reg;
            const unsigned b = (best_p[i] >> (reg * 8)) & 255u;
            float v  = best_v[r];
            int   bi = cbase0 + (int)(b >> 3) * 256 + wcol + (int)(b & 7) * 16 + m;
#pragma unroll
            for (int off = 1; off < 16; off <<= 1) {
                const float ov = __shfl_xor(v, off, 64);
                const int   oi = __shfl_xor(bi, off, 64);
                if (ov < v || (ov == v && oi < bi)) { v = ov; bi = oi; }
            }
            if (m == 0) {
                const int row = wrow + i * 16 + quad * 4 + reg;
                redv[row * 2 + (w & 1)] = v;
                redi[row * 2 + (w & 1)] = bi;
            }
        }
    __syncthreads();
    if (t < 128) {
        const float v0 = redv[t * 2], v1 = redv[t * 2 + 1];
        const int   i0 = redi[t * 2], i1 = redi[t * 2 + 1];
        const bool  b1 = (v1 < v0) || (v1 == v0 && i1 < i0);
        const size_t o = (size_t)blockIdx.y * NROWS + blockIdx.x * 128 + t;
        part_v[o] = b1 ? v1 : v0;
        part_i[o] = b1 ? i1 : i0;
    }
}

#undef STAGE
#undef COMPUTE

// ---------------------------------------------------------------- merge partials + histogram
__global__ void k_reduce_part(const float* __restrict__ pv, const int* __restrict__ pi,
                              int* __restrict__ idx_i, float* __restrict__ idx_f,
                              int* __restrict__ counts) {
    const int r = blockIdx.x * blockDim.x + threadIdx.x;
    float v = pv[r]; int bi = pi[r];
#pragma unroll
    for (int c = 1; c < NCH; ++c) {
        const float v2 = pv[(size_t)c * NROWS + r];
        const int   i2 = pi[(size_t)c * NROWS + r];
        if (v2 < v || (v2 == v && i2 < bi)) { v = v2; bi = i2; }
    }
    idx_i[r] = bi;
    idx_f[r] = (float)bi;
    atomicAdd(&counts[bi], 1);
}

// ---------------------------------------------------------------- scan + new_cluster_size + n  (1 block, 1024 thr)
__global__ void k_scan_ncs(const int* __restrict__ counts, const float* __restrict__ ema_cs,
                           int* __restrict__ offsets, float* __restrict__ ncs_out,
                           float* __restrict__ ntot) {
    __shared__ int   wsum[16];
    __shared__ float red[16];
    const int t = threadIdx.x;
    const int lane = t & 63, w = t >> 6;
    int c[8]; int s = 0; float fs = 0.0f;
#pragma unroll
    for (int u = 0; u < 8; ++u) {
        c[u] = counts[t * 8 + u]; s += c[u];
        const float v = fmaf(0.99f, ema_cs[t * 8 + u], 0.01f * (float)c[u]);
        ncs_out[t * 8 + u] = v;
        fs += v;
    }
    int inc = s;
#pragma unroll
    for (int off = 1; off < 64; off <<= 1) {
        const int n = __shfl_up(inc, off, 64);
        if (lane >= off) inc += n;
    }
#pragma unroll
    for (int off = 32; off > 0; off >>= 1) fs += __shfl_down(fs, off, 64);
    if (lane == 63) wsum[w] = inc;
    if (lane == 0)  red[w]  = fs;
    __syncthreads();
    if (t < 16) {
        int v = wsum[t];
#pragma unroll
        for (int off = 1; off < 16; off <<= 1) {
            const int n = __shfl_up(v, off, 64);
            if (t >= off) v += n;
        }
        wsum[t] = v;
        float fv = red[t];
#pragma unroll
        for (int off = 8; off > 0; off >>= 1) fv += __shfl_down(fv, off, 16);
        if (t == 0) *ntot = fv;
    }
    __syncthreads();
    int base = (w > 0 ? wsum[w - 1] : 0) + (inc - s);
#pragma unroll
    for (int u = 0; u < 8; ++u) { offsets[t * 8 + u] = base; base += c[u]; }
}

// ---------------------------------------------------------------- zq + loss partials + bucket scatter
__global__ void k_zq(const float* __restrict__ z, const float* __restrict__ emb,
                     const int* __restrict__ idx_i, const int* __restrict__ offsets,
                     int* __restrict__ cursor, int* __restrict__ buckets,
                     float* __restrict__ zq, float* __restrict__ losspart) {
    __shared__ float lred[4];
    const int t = threadIdx.x;
    const int wr = t >> 6, lane = t & 63;
    const int row = blockIdx.x * 4 + wr;
    const int code = idx_i[row];
    float4 zv = ((const float4*)z)[row * 64 + lane];
    float4 ev = ((const float4*)emb)[(size_t)code * 64 + lane];
    float4 o = make_float4(zv.x + (ev.x - zv.x), zv.y + (ev.y - zv.y),
                           zv.z + (ev.z - zv.z), zv.w + (ev.w - zv.w));
    ((float4*)zq)[row * 64 + lane] = o;
    float dx = ev.x - zv.x, dy = ev.y - zv.y, dz = ev.z - zv.z, dw = ev.w - zv.w;
    float s = fmaf(dx, dx, fmaf(dy, dy, fmaf(dz, dz, dw * dw)));
#pragma unroll
    for (int off = 32; off > 0; off >>= 1) s += __shfl_down(s, off, 64);
    if (lane == 0) {
        lred[wr] = s;
        const int pos = atomicAdd(&cursor[code], 1);
        buckets[offsets[code] + pos] = row;
    }
    __syncthreads();
    if (t == 0) losspart[blockIdx.x] = (lred[0] + lred[1]) + (lred[2] + lred[3]);
}

// ---------------------------------------------------------------- dw + new_ema_w + new_embedding (+loss tail block)
__global__ void k_dw_nemb(const float* __restrict__ z, const float* __restrict__ ema_w,
                          const int* __restrict__ counts, const int* __restrict__ offsets,
                          const int* __restrict__ buckets, const float* __restrict__ ncs,
                          const float* __restrict__ ntot_p, const float* __restrict__ losspart,
                          float* __restrict__ nemaw, float* __restrict__ nemb,
                          float* __restrict__ loss_out) {
    __shared__ float lred[4];
    if (blockIdx.x == K_CODES) {          // loss finalize
        const int t = threadIdx.x;        // 256
        float s = 0.0f;
        for (int i = t; i < 8192; i += 256) s += losspart[i];
#pragma unroll
        for (int off = 32; off > 0; off >>= 1) s += __shfl_down(s, off, 64);
        if ((t & 63) == 0) lred[t >> 6] = s;
        __syncthreads();
        if (t == 0)
            *loss_out = 0.25f * ((lred[0] + lred[1]) + (lred[2] + lred[3])) / 8388608.0f;
        return;
    }
    const int code = blockIdx.x;
    const int d    = threadIdx.x;         // 256 = DIM
    const int cnt  = counts[code];
    const int off  = offsets[code];
    float acc = 0.0f;
    for (int it = 0; it < cnt; ++it)
        acc += z[(size_t)buckets[off + it] * DIM + d];
    const float wv = fmaf(0.99f, ema_w[(size_t)code * DIM + d], 0.01f * acc);
    nemaw[(size_t)code * DIM + d] = wv;
    const float n  = *ntot_p;
    const float cs = (ncs[code] + 1e-5f) * (n / (n + (float)K_CODES * 1e-5f));
    nemb[(size_t)code * DIM + d] = wv / cs;
}

// ================================================================ fp32 fallback path (round-1 verified)
#define BM   64
#define BN   128
#define LSTR 36

__global__ void k_esq_zero_fb(const float* __restrict__ emb, float* __restrict__ esq,
                              float* __restrict__ zbuf) {
    const int gid  = blockIdx.x * blockDim.x + threadIdx.x;
    if (gid < K_CODES + 2) zbuf[gid] = 0.0f;
    const int code = gid >> 6;
    const int lane = gid & 63;
    float4 v = ((const float4*)emb)[code * 64 + lane];
    float s = fmaf(v.x, v.x, fmaf(v.y, v.y, fmaf(v.z, v.z, v.w * v.w)));
#pragma unroll
    for (int off = 32; off > 0; off >>= 1) s += __shfl_down(s, off, 64);
    if (lane == 0) esq[code] = s;
}

__global__ void k_init_nemaw_fb(const float* __restrict__ ema_w, float* __restrict__ out) {
    const int i = blockIdx.x * blockDim.x + threadIdx.x;
    float4 v = ((const float4*)ema_w)[i];
    ((float4*)out)[i] = make_float4(0.99f * v.x, 0.99f * v.y, 0.99f * v.z, 0.99f * v.w);
}

__global__ __launch_bounds__(256, 2) void k_argmin_fb(
        const float* __restrict__ z, const float* __restrict__ emb,
        const float* __restrict__ esq, int* __restrict__ idx_i, float* __restrict__ idx_f) {
    __shared__ float z_s[BM * LSTR];
    __shared__ float e_s[BN * LSTR];
    const int t = threadIdx.x, tx = t & 15, ty = t >> 4;
    const int row0 = blockIdx.x * BM;
    float best[4]; int bidx[4];
#pragma unroll
    for (int r = 0; r < 4; ++r) { best[r] = FLT_MAX; bidx[r] = 0; }
    for (int k0 = 0; k0 < K_CODES; k0 += BN) {
        float acc[4][8];
#pragma unroll
        for (int r = 0; r < 4; ++r)
#pragma unroll
            for (int c = 0; c < 8; ++c) acc[r][c] = 0.0f;
        for (int d0 = 0; d0 < DIM; d0 += 32) {
            __syncthreads();
#pragma unroll
            for (int i = 0; i < 2; ++i) {
                int f = i * 256 + t, r = f >> 3, c4 = (f & 7) << 2;
                *(float4*)&z_s[r * LSTR + c4] =
                    *(const float4*)(z + (size_t)(row0 + r) * DIM + d0 + c4);
            }
#pragma unroll
            for (int i = 0; i < 4; ++i) {
                int f = i * 256 + t, c = f >> 3, c4 = (f & 7) << 2;
                *(float4*)&e_s[c * LSTR + c4] =
                    *(const float4*)(emb + (size_t)(k0 + c) * DIM + d0 + c4);
            }
            __syncthreads();
#pragma unroll
            for (int dd = 0; dd < 32; dd += 4) {
                float4 a[4], b[8];
#pragma unroll
                for (int j = 0; j < 4; ++j)
                    a[j] = *(const float4*)&z_s[(ty * 4 + j) * LSTR + dd];
#pragma unroll
                for (int j = 0; j < 8; ++j)
                    b[j] = *(const float4*)&e_s[(tx + 16 * j) * LSTR + dd];
#pragma unroll
                for (int r = 0; r < 4; ++r)
#pragma unroll
                    for (int c = 0; c < 8; ++c) {
                        acc[r][c] = fmaf(a[r].x, b[c].x, acc[r][c]);
                        acc[r][c] = fmaf(a[r].y, b[c].y, acc[r][c]);
                        acc[r][c] = fmaf(a[r].z, b[c].z, acc[r][c]);
                        acc[r][c] = fmaf(a[r].w, b[c].w, acc[r][c]);
                    }
            }
        }
#pragma unroll
        for (int c = 0; c < 8; ++c) {
            const int code = k0 + tx + 16 * c;
            const float es = esq[code];
#pragma unroll
            for (int r = 0; r < 4; ++r) {
                float s = fmaf(-2.0f, acc[r][c], es);
                if (s < best[r] || (s == best[r] && code < bidx[r])) {
                    best[r] = s; bidx[r] = code;
                }
            }
        }
    }
    __syncthreads();
    float* rv = e_s; int* ri = (int*)z_s;
#pragma unroll
    for (int r = 0; r < 4; ++r) {
        rv[(ty * 4 + r) * 16 + tx] = best[r];
        ri[(ty * 4 + r) * 16 + tx] = bidx[r];
    }
    __syncthreads();
    if (t < 64) {
        float mv = rv[t * 16]; int mi = ri[t * 16];
#pragma unroll
        for (int i = 1; i < 16; ++i) {
            float v = rv[t * 16 + i]; int vi = ri[t * 16 + i];
            if (v < mv || (v == mv && vi < mi)) { mv = v; mi = vi; }
        }
        idx_i[row0 + t] = mi;
        idx_f[row0 + t] = (float)mi;
    }
}

__global__ void k_gather_fb(const float* __restrict__ z, const float* __restrict__ emb,
                            const int* __restrict__ idx_i, float* __restrict__ zq,
                            float* __restrict__ nemaw, float* __restrict__ counts,
                            float* __restrict__ loss) {
    const int gid  = blockIdx.x * blockDim.x + threadIdx.x;
    const int row  = gid >> 6;
    const int lane = gid & 63;
    const int code = idx_i[row];
    float4 zv = ((const float4*)z)[row * 64 + lane];
    float4 ev = ((const float4*)emb)[(size_t)code * 64 + lane];
    float4 o = make_float4(zv.x + (ev.x - zv.x), zv.y + (ev.y - zv.y),
                           zv.z + (ev.z - zv.z), zv.w + (ev.w - zv.w));
    ((float4*)zq)[row * 64 + lane] = o;
    float dx = ev.x - zv.x, dy = ev.y - zv.y, dz = ev.z - zv.z, dw = ev.w - zv.w;
    float s = fmaf(dx, dx, fmaf(dy, dy, fmaf(dz, dz, dw * dw)));
#pragma unroll
    for (int off = 32; off > 0; off >>= 1) s += __shfl_down(s, off, 64);
    if (lane == 0) { atomicAdd(loss, s); atomicAdd(&counts[code], 1.0f); }
    float* base = nemaw + (size_t)code * DIM + lane * 4;
    atomicAdd(base + 0, 0.01f * zv.x);
    atomicAdd(base + 1, 0.01f * zv.y);
    atomicAdd(base + 2, 0.01f * zv.z);
    atomicAdd(base + 3, 0.01f * zv.w);
}

__global__ void k_ncs_fb(const float* __restrict__ ema_cs, const float* __restrict__ counts,
                         float* __restrict__ ncs_out, float* __restrict__ ntot,
                         const float* __restrict__ loss_in, float* __restrict__ loss_out) {
    __shared__ float red[16];
    const int t = threadIdx.x;
    float s = 0.0f;
    for (int i = t; i < K_CODES; i += 1024) {
        float v = fmaf(0.99f, ema_cs[i], 0.01f * counts[i]);
        ncs_out[i] = v; s += v;
    }
#pragma unroll
    for (int off = 32; off > 0; off >>= 1) s += __shfl_down(s, off, 64);
    if ((t & 63) == 0) red[t >> 6] = s;
    __syncthreads();
    if (t < 16) {
        float v = red[t];
#pragma unroll
        for (int off = 8; off > 0; off >>= 1) v += __shfl_down(v, off, 16);
        if (t == 0) { *ntot = v; *loss_out = 0.25f * (*loss_in) / 8388608.0f; }
    }
}

__global__ void k_nemb_fb(const float* __restrict__ nemaw, const float* __restrict__ ncs,
                          const float* __restrict__ ntot_p, float* __restrict__ nemb) {
    const int i4 = blockIdx.x * blockDim.x + threadIdx.x;
    const int k  = i4 >> 6;
    const float n   = *ntot_p;
    const float inv = n / (n + (float)K_CODES * 1e-5f);
    const float cs  = (ncs[k] + 1e-5f) * inv;
    float4 wv = ((const float4*)nemaw)[i4];
    ((float4*)nemb)[i4] = make_float4(wv.x / cs, wv.y / cs, wv.z / cs, wv.w / cs);
}

extern "C" void kernel_launch(void* const* d_in, const int* in_sizes, int n_in,
                              void* d_out, int out_size, void* d_ws, size_t ws_size,
                              hipStream_t stream) {
    const float* z      = (const float*)d_in[0];
    const float* emb    = (const float*)d_in[1];
    const float* ema_cs = (const float*)d_in[2];
    const float* ema_w  = (const float*)d_in[3];
    float* out = (float*)d_out;
    char* wsb = (char*)d_ws;

    // ---- MFMA-path workspace layout (bytes), total 43,417,616 (NCH=2 uses
    // only half of part_v/part_i but offsets kept from r3 layout)
    unsigned short* zcat    = (unsigned short*)wsb;                  // 33,554,432
    unsigned short* ecat    = (unsigned short*)(wsb + 33554432);     //  8,388,608
    float*          part_v  = (float*)(wsb + 41943040);              //    524,288
    int*            part_i  = (int*)  (wsb + 42467328);              //    524,288
    float*          esq     = (float*)(wsb + 42991616);              //     32,768
    int*            ws_idx  = (int*)  (wsb + 43024384);              //    131,072
    int*            counts  = (int*)  (wsb + 43155456);              //     32,768
    int*            cursor  = (int*)  (wsb + 43188224);              //     32,768 (contiguous w/ counts)
    int*            offsets = (int*)  (wsb + 43220992);              //     32,768
    int*            buckets = (int*)  (wsb + 43253760);              //    131,072
    float*          lpart   = (float*)(wsb + 43384832);              //     32,768
    float*          ws_loss = (float*)(wsb + 43417600);
    float*          ws_ntot = ws_loss + 1;

    if (ws_size >= (size_t)43417616) {
        k_prep       <<<10240, 256, 0, stream>>>(z, emb, zcat, ecat, esq, counts);
        k_argmin_mfma<<<dim3(NROWS / 128, NCH), 256, 0, stream>>>(
            zcat, ecat, esq, part_v, part_i);
        k_reduce_part<<<NROWS / 256, 256, 0, stream>>>(part_v, part_i, ws_idx,
                                                       out + O_IDX, counts);
        k_scan_ncs   <<<1, 1024, 0, stream>>>(counts, ema_cs, offsets,
                                              out + O_NCS, ws_ntot);
        k_zq         <<<NROWS / 4, 256, 0, stream>>>(z, emb, ws_idx, offsets, cursor,
                                                     buckets, out + O_ZQ, lpart);
        k_dw_nemb    <<<K_CODES + 1, 256, 0, stream>>>(z, ema_w, counts, offsets, buckets,
                                                       out + O_NCS, ws_ntot, lpart,
                                                       out + O_NEMAW, out + O_NEMB,
                                                       out + O_LOSS);
    } else {
        // small-ws fallback (round-1 verified fp32 path)
        int*   f_idx    = (int*)wsb;
        float* f_counts = (float*)(wsb + 131072);
        float* f_loss   = f_counts + K_CODES;
        float* f_ntot   = f_loss + 1;
        float* f_esq    = (float*)(wsb + 163856);
        k_esq_zero_fb  <<<2048, 256, 0, stream>>>(emb, f_esq, f_counts);
        k_init_nemaw_fb<<<2048, 256, 0, stream>>>(ema_w, out + O_NEMAW);
        k_argmin_fb    <<<NROWS / BM, 256, 0, stream>>>(z, emb, f_esq, f_idx, out + O_IDX);
        k_gather_fb    <<<NROWS / 4, 256, 0, stream>>>(z, emb, f_idx, out + O_ZQ,
                                                       out + O_NEMAW, f_counts, f_loss);
        k_ncs_fb       <<<1, 1024, 0, stream>>>(ema_cs, f_counts, out + O_NCS, f_ntot,
                                                f_loss, out + O_LOSS);
        k_nemb_fb      <<<2048, 256, 0, stream>>>(out + O_NEMAW, out + O_NCS, f_ntot,
                                                  out + O_NEMB);
    }
}

// Round 2
// 751.526 us; speedup vs baseline: 1.0474x; 1.0474x over previous
//
#include <hip/hip_runtime.h>
#include <cfloat>

// VQ-VAE vector quantizer. Round 7: round-6's 2-phase double-buffered pipeline
// regressed due to scratch spill (WRITE_SIZE 512KB -> 271MB). Keep the
// pipeline, cut arch-VGPR pressure back under the 128-reg budget:
//   - no es[] prefetch (esq re-read at acc-init, L2-resident, like round 5)
//   - COMPUTE streams A-fragments one at a time against 8 resident B-fragments
//     (peak fragment live set 48 -> 36 regs)
// N=32768 rows, K=8192 codes, D=256.
#define K_CODES 8192
#define DIM     256
#define NROWS   32768

// d_out float offsets (outputs concatenated in reference return order)
#define O_ZQ    0
#define O_LOSS  8388608
#define O_IDX   8388609
#define O_NEMB  8421377
#define O_NCS   10518529
#define O_NEMAW 10526721

// ---- MFMA path params
#define NCH          2                    // code chunks
#define CODES_PER_CH (K_CODES / NCH)      // 4096
#define NT_TILES     (CODES_PER_CH / 256) // 16

typedef __attribute__((ext_vector_type(8))) short short8;
typedef __attribute__((ext_vector_type(4))) float floatx4;

__device__ __forceinline__ unsigned short f2bf_rne(float x) {
    unsigned u = __float_as_uint(x);
    u += 0x7fffu + ((u >> 16) & 1u);
    return (unsigned short)(u >> 16);
}
__device__ __forceinline__ float bf2f(unsigned short h) {
    return __uint_as_float(((unsigned)h) << 16);
}
__device__ __forceinline__ void async16(const void* g, void* l) {
    __builtin_amdgcn_global_load_lds(
        (const __attribute__((address_space(1))) void*)g,
        (__attribute__((address_space(3))) void*)l, 16, 0, 0);
}

// ---------------------------------------------------------------- fused convert: z & emb -> {hi,lo} bf16 + |e|^2 + zero
__global__ void k_prep(const float* __restrict__ z, const float* __restrict__ emb,
                       unsigned short* __restrict__ zcat, unsigned short* __restrict__ ecat,
                       float* __restrict__ esq, int* __restrict__ zero16k) {
    const int b = blockIdx.x;
    if (b < 8192) {
        const int i = b * 256 + threadIdx.x;         // float4 idx, 2,097,152
        const int row = i >> 6;
        const int col = (i & 63) << 2;
        float4 v = ((const float4*)z)[i];
        // fold -2 into z: bf16(-2z) == -2*bf16(z) exactly (pow2 scale)
        float nx = -2.0f * v.x, ny = -2.0f * v.y, nz = -2.0f * v.z, nw = -2.0f * v.w;
        ushort4 h, l;
        h.x = f2bf_rne(nx); l.x = f2bf_rne(nx - bf2f(h.x));
        h.y = f2bf_rne(ny); l.y = f2bf_rne(ny - bf2f(h.y));
        h.z = f2bf_rne(nz); l.z = f2bf_rne(nz - bf2f(h.z));
        h.w = f2bf_rne(nw); l.w = f2bf_rne(nw - bf2f(h.w));
        *(ushort4*)&zcat[(size_t)row * 512 + col]       = h;
        *(ushort4*)&zcat[(size_t)row * 512 + 256 + col] = l;
    } else {
        const int gid  = (b - 8192) * 256 + threadIdx.x;  // 0..524287
        if (gid < 2 * K_CODES) zero16k[gid] = 0;          // counts + cursor
        const int code = gid >> 6;
        const int lane = gid & 63;
        const int col  = lane << 2;
        float4 v = ((const float4*)emb)[code * 64 + lane];
        ushort4 h, l;
        h.x = f2bf_rne(v.x); l.x = f2bf_rne(v.x - bf2f(h.x));
        h.y = f2bf_rne(v.y); l.y = f2bf_rne(v.y - bf2f(h.y));
        h.z = f2bf_rne(v.z); l.z = f2bf_rne(v.z - bf2f(h.z));
        h.w = f2bf_rne(v.w); l.w = f2bf_rne(v.w - bf2f(h.w));
        *(ushort4*)&ecat[(size_t)code * 512 + col]       = h;
        *(ushort4*)&ecat[(size_t)code * 512 + 256 + col] = l;
        float s = fmaf(v.x, v.x, fmaf(v.y, v.y, fmaf(v.z, v.z, v.w * v.w)));
#pragma unroll
        for (int off = 32; off > 0; off >>= 1) s += __shfl_down(s, off, 64);
        if (lane == 0) esq[code] = s;
    }
}

// ---------------------------------------------------------------- MFMA argmin GEMM (virtual K=768, BK=32, 128x256 tile)
// score(n,k) = esq[k] + dot(zcat_n, ecat_k segs), zcat encodes -2z.
// A segs {hi,hi,lo}: off_a=(k0&255)|((k0&512)>>1); B segs {hi,lo,hi}: off_b=k0&511.
// 2-phase double-buffered pipeline: stage step s+1 (global_load_lds into
// buf^1) issued BEFORE compute of step s (ds_read from buf); the single
// __syncthreads() per step drains the prefetch after it hid under 32 MFMAs.
// LDS layout (BK=32, 64B rows of 4x16B chunks): logical chunk c of row R at
// physical chunk c ^ ((R>>1)&3). Per aligned 8-lane phase group the b128
// reads cover 8 distinct 16B slots (even m -> banks 0-15, odd m -> 16-31):
// conflict-free (verified r6: SQ_LDS_BANK_CONFLICT=0). Stage pre-swizzles
// the GLOBAL source (linear LDS dest, as global_load_lds requires).
// 4 waves, wave-tile 64x128: wrow=(w>>1)*64, wcol=(w&1)*128, acc 4x8 of 16x16x32.
#define STAGE(AS, BS, ntv, offa, offb)                                          \
    do {                                                                        \
        _Pragma("unroll")                                                       \
        for (int c_ = 0; c_ < 6; ++c_) {                                        \
            const int u_ = w * 6 + c_;                                          \
            if (u_ < 8)                                                         \
                async16(aGlob + (size_t)u_ * 8192 + (offa), &AS[u_ * 512]);     \
            else                                                                \
                async16(bGlob + (size_t)(ntv) * 131072 +                        \
                            (size_t)(u_ - 8) * 8192 + (offb),                   \
                        &BS[(u_ - 8) * 512]);                                   \
        }                                                                       \
    } while (0)

// B fragments resident (32 VGPR), A streamed one at a time (4 VGPR):
// peak fragment live set 36 regs (was 48) to stay under the 128-VGPR budget.
#define COMPUTE(AS, BS)                                                         \
    do {                                                                        \
        short8 bf_[8];                                                          \
        _Pragma("unroll")                                                       \
        for (int j_ = 0; j_ < 8; ++j_)                                          \
            bf_[j_] = *(const short8*)&BS[(wcol + j_ * 16 + m) * 32 + xo];      \
        _Pragma("unroll")                                                       \
        for (int i_ = 0; i_ < 4; ++i_) {                                        \
            const short8 af_ =                                                  \
                *(const short8*)&AS[(wrow + i_ * 16 + m) * 32 + xo];            \
            _Pragma("unroll")                                                   \
            for (int j_ = 0; j_ < 8; ++j_)                                      \
                acc[i_][j_] = __builtin_amdgcn_mfma_f32_16x16x32_bf16(          \
                    af_, bf_[j_], acc[i_][j_], 0, 0, 0);                        \
        }                                                                       \
    } while (0)

__global__ __launch_bounds__(256, 2) void k_argmin_mfma(
        const unsigned short* __restrict__ zcat, const unsigned short* __restrict__ ecat,
        const float* __restrict__ esq,
        float* __restrict__ part_v, int* __restrict__ part_i) {
    // double buffer as SEPARATE arrays (alias analysis keeps stage/compute
    // independent). A: 128x32 ushort = 8 KB each; B: 256x32 = 16 KB each.
    __shared__ __align__(16) unsigned short a0_s[128 * 32];
    __shared__ __align__(16) unsigned short a1_s[128 * 32];
    __shared__ __align__(16) unsigned short b0_s[256 * 32];
    __shared__ __align__(16) unsigned short b1_s[256 * 32];
    const int t    = threadIdx.x;
    const int w    = t >> 6;
    const int lane = t & 63;
    const int quad = lane >> 4;
    const int m    = lane & 15;
    const int wrow = (w >> 1) * 64;
    const int wcol = (w & 1) * 128;
    const int row0   = blockIdx.x * 128;
    const int cbase0 = blockIdx.y * CODES_PER_CH;

    // staging geometry: 1536 16B slots/step (512 A + 1024 B) = 24 wave-chunks
    // of 64 slots; wave w takes u = w*6..w*6+5 (u<8 -> A rows u*16.., else B
    // rows (u-8)*16..). Lane covers slot (prow=lane>>2, pchunk=lane&3) which
    // holds logical chunk (lane&3) ^ ((lane>>3)&3) of its row.
    const int    swz    = (((lane & 3) ^ ((lane >> 3) & 3)) << 3);  // ushorts
    const size_t srcrow = (size_t)(lane >> 2) * 512 + swz;
    const unsigned short* aGlob = zcat + (size_t)row0 * 512 + srcrow;
    const unsigned short* bGlob = ecat + (size_t)cbase0 * 512 + srcrow;

    // fragment-read swizzle: physical chunk = quad ^ ((m>>1)&3), kk-invariant
    const int xo = ((quad ^ ((m >> 1) & 3)) << 3);

    float    best_v[16];
    unsigned best_p[4];     // per i: 4 reg-slots x 8-bit candidate (nt*8+j)
#pragma unroll
    for (int r = 0; r < 16; ++r) best_v[r] = FLT_MAX;
#pragma unroll
    for (int i = 0; i < 4; ++i) best_p[i] = 0u;

    // prologue: stage (nt=0, k0=0) into buf0
    STAGE(a0_s, b0_s, 0, 0, 0);
    __syncthreads();   // drains prologue stage (vmcnt 0 at barrier)

    for (int nt = 0; nt < NT_TILES; ++nt) {
        const int cb = cbase0 + nt * 256;
        floatx4 acc[4][8];
#pragma unroll
        for (int j = 0; j < 8; ++j) {
            const float es = esq[cb + wcol + j * 16 + m];
#pragma unroll
            for (int i = 0; i < 4; ++i) acc[i][j] = (floatx4){es, es, es, es};
        }

        for (int kk2 = 0; kk2 < 12; ++kk2) {
            {   // step A: stage k0=64*kk2+32 into buf1, compute 64*kk2 from buf0
                const int nk0 = kk2 * 64 + 32;
                STAGE(a1_s, b1_s, nt, (nk0 & 255) | ((nk0 & 512) >> 1), nk0 & 511);
                COMPUTE(a0_s, b0_s);
                __syncthreads();
            }
            {   // step B: stage next step into buf0, compute from buf1
                if (kk2 < 11) {
                    const int nk0 = kk2 * 64 + 64;
                    STAGE(a0_s, b0_s, nt, (nk0 & 255) | ((nk0 & 512) >> 1), nk0 & 511);
                } else if (nt + 1 < NT_TILES) {
                    STAGE(a0_s, b0_s, nt + 1, 0, 0);    // first step of next nt
                }
                COMPUTE(a1_s, b1_s);
                __syncthreads();
            }
        }
        // epilogue: acc IS the score. codes ascend in (nt,j): strict < = first-min.
#pragma unroll
        for (int j = 0; j < 8; ++j) {
            const unsigned cand = (unsigned)(nt * 8 + j);   // 7 bits
#pragma unroll
            for (int i = 0; i < 4; ++i)
#pragma unroll
                for (int reg = 0; reg < 4; ++reg) {
                    const float s = acc[i][j][reg];
                    const int r = i * 4 + reg;
                    if (s < best_v[r]) {
                        best_v[r] = s;
                        best_p[i] = (best_p[i] & ~(255u << (reg * 8))) | (cand << (reg * 8));
                    }
                }
        }
    }
    // reconstruct codes, butterfly across the 16 lanes sharing each row
    __syncthreads();               // staging LDS free for reuse
    float* redv = (float*)a0_s;    // [128][2]
    int*   redi = (int*)b0_s;      // [128][2]
#pragma unroll
    for (int i = 0; i < 4; ++i)
#pragma unroll
        for (int reg = 0; reg < 4; ++reg) {
            const int r = i * 4 + reg;
            const unsigned b = (best_p[i] >> (reg * 8)) & 255u;
            float v  = best_v[r];
            int   bi = cbase0 + (int)(b >> 3) * 256 + wcol + (int)(b & 7) * 16 + m;
#pragma unroll
            for (int off = 1; off < 16; off <<= 1) {
                const float ov = __shfl_xor(v, off, 64);
                const int   oi = __shfl_xor(bi, off, 64);
                if (ov < v || (ov == v && oi < bi)) { v = ov; bi = oi; }
            }
            if (m == 0) {
                const int row = wrow + i * 16 + quad * 4 + reg;
                redv[row * 2 + (w & 1)] = v;
                redi[row * 2 + (w & 1)] = bi;
            }
        }
    __syncthreads();
    if (t < 128) {
        const float v0 = redv[t * 2], v1 = redv[t * 2 + 1];
        const int   i0 = redi[t * 2], i1 = redi[t * 2 + 1];
        const bool  b1 = (v1 < v0) || (v1 == v0 && i1 < i0);
        const size_t o = (size_t)blockIdx.y * NROWS + blockIdx.x * 128 + t;
        part_v[o] = b1 ? v1 : v0;
        part_i[o] = b1 ? i1 : i0;
    }
}

#undef STAGE
#undef COMPUTE

// ---------------------------------------------------------------- merge partials + histogram
__global__ void k_reduce_part(const float* __restrict__ pv, const int* __restrict__ pi,
                              int* __restrict__ idx_i, float* __restrict__ idx_f,
                              int* __restrict__ counts) {
    const int r = blockIdx.x * blockDim.x + threadIdx.x;
    float v = pv[r]; int bi = pi[r];
#pragma unroll
    for (int c = 1; c < NCH; ++c) {
        const float v2 = pv[(size_t)c * NROWS + r];
        const int   i2 = pi[(size_t)c * NROWS + r];
        if (v2 < v || (v2 == v && i2 < bi)) { v = v2; bi = i2; }
    }
    idx_i[r] = bi;
    idx_f[r] = (float)bi;
    atomicAdd(&counts[bi], 1);
}

// ---------------------------------------------------------------- scan + new_cluster_size + n  (1 block, 1024 thr)
__global__ void k_scan_ncs(const int* __restrict__ counts, const float* __restrict__ ema_cs,
                           int* __restrict__ offsets, float* __restrict__ ncs_out,
                           float* __restrict__ ntot) {
    __shared__ int   wsum[16];
    __shared__ float red[16];
    const int t = threadIdx.x;
    const int lane = t & 63, w = t >> 6;
    int c[8]; int s = 0; float fs = 0.0f;
#pragma unroll
    for (int u = 0; u < 8; ++u) {
        c[u] = counts[t * 8 + u]; s += c[u];
        const float v = fmaf(0.99f, ema_cs[t * 8 + u], 0.01f * (float)c[u]);
        ncs_out[t * 8 + u] = v;
        fs += v;
    }
    int inc = s;
#pragma unroll
    for (int off = 1; off < 64; off <<= 1) {
        const int n = __shfl_up(inc, off, 64);
        if (lane >= off) inc += n;
    }
#pragma unroll
    for (int off = 32; off > 0; off >>= 1) fs += __shfl_down(fs, off, 64);
    if (lane == 63) wsum[w] = inc;
    if (lane == 0)  red[w]  = fs;
    __syncthreads();
    if (t < 16) {
        int v = wsum[t];
#pragma unroll
        for (int off = 1; off < 16; off <<= 1) {
            const int n = __shfl_up(v, off, 64);
            if (t >= off) v += n;
        }
        wsum[t] = v;
        float fv = red[t];
#pragma unroll
        for (int off = 8; off > 0; off >>= 1) fv += __shfl_down(fv, off, 16);
        if (t == 0) *ntot = fv;
    }
    __syncthreads();
    int base = (w > 0 ? wsum[w - 1] : 0) + (inc - s);
#pragma unroll
    for (int u = 0; u < 8; ++u) { offsets[t * 8 + u] = base; base += c[u]; }
}

// ---------------------------------------------------------------- zq + loss partials + bucket scatter
__global__ void k_zq(const float* __restrict__ z, const float* __restrict__ emb,
                     const int* __restrict__ idx_i, const int* __restrict__ offsets,
                     int* __restrict__ cursor, int* __restrict__ buckets,
                     float* __restrict__ zq, float* __restrict__ losspart) {
    __shared__ float lred[4];
    const int t = threadIdx.x;
    const int wr = t >> 6, lane = t & 63;
    const int row = blockIdx.x * 4 + wr;
    const int code = idx_i[row];
    float4 zv = ((const float4*)z)[row * 64 + lane];
    float4 ev = ((const float4*)emb)[(size_t)code * 64 + lane];
    float4 o = make_float4(zv.x + (ev.x - zv.x), zv.y + (ev.y - zv.y),
                           zv.z + (ev.z - zv.z), zv.w + (ev.w - zv.w));
    ((float4*)zq)[row * 64 + lane] = o;
    float dx = ev.x - zv.x, dy = ev.y - zv.y, dz = ev.z - zv.z, dw = ev.w - zv.w;
    float s = fmaf(dx, dx, fmaf(dy, dy, fmaf(dz, dz, dw * dw)));
#pragma unroll
    for (int off = 32; off > 0; off >>= 1) s += __shfl_down(s, off, 64);
    if (lane == 0) {
        lred[wr] = s;
        const int pos = atomicAdd(&cursor[code], 1);
        buckets[offsets[code] + pos] = row;
    }
    __syncthreads();
    if (t == 0) losspart[blockIdx.x] = (lred[0] + lred[1]) + (lred[2] + lred[3]);
}

// ---------------------------------------------------------------- dw + new_ema_w + new_embedding (+loss tail block)
__global__ void k_dw_nemb(const float* __restrict__ z, const float* __restrict__ ema_w,
                          const int* __restrict__ counts, const int* __restrict__ offsets,
                          const int* __restrict__ buckets, const float* __restrict__ ncs,
                          const float* __restrict__ ntot_p, const float* __restrict__ losspart,
                          float* __restrict__ nemaw, float* __restrict__ nemb,
                          float* __restrict__ loss_out) {
    __shared__ float lred[4];
    if (blockIdx.x == K_CODES) {          // loss finalize
        const int t = threadIdx.x;        // 256
        float s = 0.0f;
        for (int i = t; i < 8192; i += 256) s += losspart[i];
#pragma unroll
        for (int off = 32; off > 0; off >>= 1) s += __shfl_down(s, off, 64);
        if ((t & 63) == 0) lred[t >> 6] = s;
        __syncthreads();
        if (t == 0)
            *loss_out = 0.25f * ((lred[0] + lred[1]) + (lred[2] + lred[3])) / 8388608.0f;
        return;
    }
    const int code = blockIdx.x;
    const int d    = threadIdx.x;         // 256 = DIM
    const int cnt  = counts[code];
    const int off  = offsets[code];
    float acc = 0.0f;
    for (int it = 0; it < cnt; ++it)
        acc += z[(size_t)buckets[off + it] * DIM + d];
    const float wv = fmaf(0.99f, ema_w[(size_t)code * DIM + d], 0.01f * acc);
    nemaw[(size_t)code * DIM + d] = wv;
    const float n  = *ntot_p;
    const float cs = (ncs[code] + 1e-5f) * (n / (n + (float)K_CODES * 1e-5f));
    nemb[(size_t)code * DIM + d] = wv / cs;
}

// ================================================================ fp32 fallback path (round-1 verified)
#define BM   64
#define BN   128
#define LSTR 36

__global__ void k_esq_zero_fb(const float* __restrict__ emb, float* __restrict__ esq,
                              float* __restrict__ zbuf) {
    const int gid  = blockIdx.x * blockDim.x + threadIdx.x;
    if (gid < K_CODES + 2) zbuf[gid] = 0.0f;
    const int code = gid >> 6;
    const int lane = gid & 63;
    float4 v = ((const float4*)emb)[code * 64 + lane];
    float s = fmaf(v.x, v.x, fmaf(v.y, v.y, fmaf(v.z, v.z, v.w * v.w)));
#pragma unroll
    for (int off = 32; off > 0; off >>= 1) s += __shfl_down(s, off, 64);
    if (lane == 0) esq[code] = s;
}

__global__ void k_init_nemaw_fb(const float* __restrict__ ema_w, float* __restrict__ out) {
    const int i = blockIdx.x * blockDim.x + threadIdx.x;
    float4 v = ((const float4*)ema_w)[i];
    ((float4*)out)[i] = make_float4(0.99f * v.x, 0.99f * v.y, 0.99f * v.z, 0.99f * v.w);
}

__global__ __launch_bounds__(256, 2) void k_argmin_fb(
        const float* __restrict__ z, const float* __restrict__ emb,
        const float* __restrict__ esq, int* __restrict__ idx_i, float* __restrict__ idx_f) {
    __shared__ float z_s[BM * LSTR];
    __shared__ float e_s[BN * LSTR];
    const int t = threadIdx.x, tx = t & 15, ty = t >> 4;
    const int row0 = blockIdx.x * BM;
    float best[4]; int bidx[4];
#pragma unroll
    for (int r = 0; r < 4; ++r) { best[r] = FLT_MAX; bidx[r] = 0; }
    for (int k0 = 0; k0 < K_CODES; k0 += BN) {
        float acc[4][8];
#pragma unroll
        for (int r = 0; r < 4; ++r)
#pragma unroll
            for (int c = 0; c < 8; ++c) acc[r][c] = 0.0f;
        for (int d0 = 0; d0 < DIM; d0 += 32) {
            __syncthreads();
#pragma unroll
            for (int i = 0; i < 2; ++i) {
                int f = i * 256 + t, r = f >> 3, c4 = (f & 7) << 2;
                *(float4*)&z_s[r * LSTR + c4] =
                    *(const float4*)(z + (size_t)(row0 + r) * DIM + d0 + c4);
            }
#pragma unroll
            for (int i = 0; i < 4; ++i) {
                int f = i * 256 + t, c = f >> 3, c4 = (f & 7) << 2;
                *(float4*)&e_s[c * LSTR + c4] =
                    *(const float4*)(emb + (size_t)(k0 + c) * DIM + d0 + c4);
            }
            __syncthreads();
#pragma unroll
            for (int dd = 0; dd < 32; dd += 4) {
                float4 a[4], b[8];
#pragma unroll
                for (int j = 0; j < 4; ++j)
                    a[j] = *(const float4*)&z_s[(ty * 4 + j) * LSTR + dd];
#pragma unroll
                for (int j = 0; j < 8; ++j)
                    b[j] = *(const float4*)&e_s[(tx + 16 * j) * LSTR + dd];
#pragma unroll
                for (int r = 0; r < 4; ++r)
#pragma unroll
                    for (int c = 0; c < 8; ++c) {
                        acc[r][c] = fmaf(a[r].x, b[c].x, acc[r][c]);
                        acc[r][c] = fmaf(a[r].y, b[c].y, acc[r][c]);
                        acc[r][c] = fmaf(a[r].z, b[c].z, acc[r][c]);
                        acc[r][c] = fmaf(a[r].w, b[c].w, acc[r][c]);
                    }
            }
        }
#pragma unroll
        for (int c = 0; c < 8; ++c) {
            const int code = k0 + tx + 16 * c;
            const float es = esq[code];
#pragma unroll
            for (int r = 0; r < 4; ++r) {
                float s = fmaf(-2.0f, acc[r][c], es);
                if (s < best[r] || (s == best[r] && code < bidx[r])) {
                    best[r] = s; bidx[r] = code;
                }
            }
        }
    }
    __syncthreads();
    float* rv = e_s; int* ri = (int*)z_s;
#pragma unroll
    for (int r = 0; r < 4; ++r) {
        rv[(ty * 4 + r) * 16 + tx] = best[r];
        ri[(ty * 4 + r) * 16 + tx] = bidx[r];
    }
    __syncthreads();
    if (t < 64) {
        float mv = rv[t * 16]; int mi = ri[t * 16];
#pragma unroll
        for (int i = 1; i < 16; ++i) {
            float v = rv[t * 16 + i]; int vi = ri[t * 16 + i];
            if (v < mv || (v == mv && vi < mi)) { mv = v; mi = vi; }
        }
        idx_i[row0 + t] = mi;
        idx_f[row0 + t] = (float)mi;
    }
}

__global__ void k_gather_fb(const float* __restrict__ z, const float* __restrict__ emb,
                            const int* __restrict__ idx_i, float* __restrict__ zq,
                            float* __restrict__ nemaw, float* __restrict__ counts,
                            float* __restrict__ loss) {
    const int gid  = blockIdx.x * blockDim.x + threadIdx.x;
    const int row  = gid >> 6;
    const int lane = gid & 63;
    const int code = idx_i[row];
    float4 zv = ((const float4*)z)[row * 64 + lane];
    float4 ev = ((const float4*)emb)[(size_t)code * 64 + lane];
    float4 o = make_float4(zv.x + (ev.x - zv.x), zv.y + (ev.y - zv.y),
                           zv.z + (ev.z - zv.z), zv.w + (ev.w - zv.w));
    ((float4*)zq)[row * 64 + lane] = o;
    float dx = ev.x - zv.x, dy = ev.y - zv.y, dz = ev.z - zv.z, dw = ev.w - zv.w;
    float s = fmaf(dx, dx, fmaf(dy, dy, fmaf(dz, dz, dw * dw)));
#pragma unroll
    for (int off = 32; off > 0; off >>= 1) s += __shfl_down(s, off, 64);
    if (lane == 0) { atomicAdd(loss, s); atomicAdd(&counts[code], 1.0f); }
    float* base = nemaw + (size_t)code * DIM + lane * 4;
    atomicAdd(base + 0, 0.01f * zv.x);
    atomicAdd(base + 1, 0.01f * zv.y);
    atomicAdd(base + 2, 0.01f * zv.z);
    atomicAdd(base + 3, 0.01f * zv.w);
}

__global__ void k_ncs_fb(const float* __restrict__ ema_cs, const float* __restrict__ counts,
                         float* __restrict__ ncs_out, float* __restrict__ ntot,
                         const float* __restrict__ loss_in, float* __restrict__ loss_out) {
    __shared__ float red[16];
    const int t = threadIdx.x;
    float s = 0.0f;
    for (int i = t; i < K_CODES; i += 1024) {
        float v = fmaf(0.99f, ema_cs[i], 0.01f * counts[i]);
        ncs_out[i] = v; s += v;
    }
#pragma unroll
    for (int off = 32; off > 0; off >>= 1) s += __shfl_down(s, off, 64);
    if ((t & 63) == 0) red[t >> 6] = s;
    __syncthreads();
    if (t < 16) {
        float v = red[t];
#pragma unroll
        for (int off = 8; off > 0; off >>= 1) v += __shfl_down(v, off, 16);
        if (t == 0) { *ntot = v; *loss_out = 0.25f * (*loss_in) / 8388608.0f; }
    }
}

__global__ void k_nemb_fb(const float* __restrict__ nemaw, const float* __restrict__ ncs,
                          const float* __restrict__ ntot_p, float* __restrict__ nemb) {
    const int i4 = blockIdx.x * blockDim.x + threadIdx.x;
    const int k  = i4 >> 6;
    const float n   = *ntot_p;
    const float inv = n / (n + (float)K_CODES * 1e-5f);
    const float cs  = (ncs[k] + 1e-5f) * inv;
    float4 wv = ((const float4*)nemaw)[i4];
    ((float4*)nemb)[i4] = make_float4(wv.x / cs, wv.y / cs, wv.z / cs, wv.w / cs);
}

extern "C" void kernel_launch(void* const* d_in, const int* in_sizes, int n_in,
                              void* d_out, int out_size, void* d_ws, size_t ws_size,
                              hipStream_t stream) {
    const float* z      = (const float*)d_in[0];
    const float* emb    = (const float*)d_in[1];
    const float* ema_cs = (const float*)d_in[2];
    const float* ema_w  = (const float*)d_in[3];
    float* out = (float*)d_out;
    char* wsb = (char*)d_ws;

    // ---- MFMA-path workspace layout (bytes), total 43,417,616 (NCH=2 uses
    // only half of part_v/part_i but offsets kept from r3 layout)
    unsigned short* zcat    = (unsigned short*)wsb;                  // 33,554,432
    unsigned short* ecat    = (unsigned short*)(wsb + 33554432);     //  8,388,608
    float*          part_v  = (float*)(wsb + 41943040);              //    524,288
    int*            part_i  = (int*)  (wsb + 42467328);              //    524,288
    float*          esq     = (float*)(wsb + 42991616);              //     32,768
    int*            ws_idx  = (int*)  (wsb + 43024384);              //    131,072
    int*            counts  = (int*)  (wsb + 43155456);              //     32,768
    int*            cursor  = (int*)  (wsb + 43188224);              //     32,768 (contiguous w/ counts)
    int*            offsets = (int*)  (wsb + 43220992);              //     32,768
    int*            buckets = (int*)  (wsb + 43253760);              //    131,072
    float*          lpart   = (float*)(wsb + 43384832);              //     32,768
    float*          ws_loss = (float*)(wsb + 43417600);
    float*          ws_ntot = ws_loss + 1;

    if (ws_size >= (size_t)43417616) {
        k_prep       <<<10240, 256, 0, stream>>>(z, emb, zcat, ecat, esq, counts);
        k_argmin_mfma<<<dim3(NROWS / 128, NCH), 256, 0, stream>>>(
            zcat, ecat, esq, part_v, part_i);
        k_reduce_part<<<NROWS / 256, 256, 0, stream>>>(part_v, part_i, ws_idx,
                                                       out + O_IDX, counts);
        k_scan_ncs   <<<1, 1024, 0, stream>>>(counts, ema_cs, offsets,
                                              out + O_NCS, ws_ntot);
        k_zq         <<<NROWS / 4, 256, 0, stream>>>(z, emb, ws_idx, offsets, cursor,
                                                     buckets, out + O_ZQ, lpart);
        k_dw_nemb    <<<K_CODES + 1, 256, 0, stream>>>(z, ema_w, counts, offsets, buckets,
                                                       out + O_NCS, ws_ntot, lpart,
                                                       out + O_NEMAW, out + O_NEMB,
                                                       out + O_LOSS);
    } else {
        // small-ws fallback (round-1 verified fp32 path)
        int*   f_idx    = (int*)wsb;
        float* f_counts = (float*)(wsb + 131072);
        float* f_loss   = f_counts + K_CODES;
        float* f_ntot   = f_loss + 1;
        float* f_esq    = (float*)(wsb + 163856);
        k_esq_zero_fb  <<<2048, 256, 0, stream>>>(emb, f_esq, f_counts);
        k_init_nemaw_fb<<<2048, 256, 0, stream>>>(ema_w, out + O_NEMAW);
        k_argmin_fb    <<<NROWS / BM, 256, 0, stream>>>(z, emb, f_esq, f_idx, out + O_IDX);
        k_gather_fb    <<<NROWS / 4, 256, 0, stream>>>(z, emb, f_idx, out + O_ZQ,
                                                       out + O_NEMAW, f_counts, f_loss);
        k_ncs_fb       <<<1, 1024, 0, stream>>>(ema_cs, f_counts, out + O_NCS, f_ntot,
                                                f_loss, out + O_LOSS);
        k_nemb_fb      <<<2048, 256, 0, stream>>>(out + O_NEMAW, out + O_NCS, f_ntot,
                                                  out + O_NEMB);
    }
}

// Round 3
// 670.545 us; speedup vs baseline: 1.1739x; 1.1208x over previous
//
#include <hip/hip_runtime.h>
#include <cfloat>

// VQ-VAE vector quantizer. Round 8: r6/r7's pipeline spill traced to FULL
// UNROLL of the kk2 loop (constant trip count) -> compiler hoists dozens of
// 64-bit staging addresses, blowing the 128-arch-VGPR cap (acc holds the
// other 128 as AGPRs). Fix: #pragma unroll 1 on kk2 + per-nt hoisted B base
// pointer. Schedule semantics identical to r7 (verified correct twice).
// N=32768 rows, K=8192 codes, D=256.
#define K_CODES 8192
#define DIM     256
#define NROWS   32768

// d_out float offsets (outputs concatenated in reference return order)
#define O_ZQ    0
#define O_LOSS  8388608
#define O_IDX   8388609
#define O_NEMB  8421377
#define O_NCS   10518529
#define O_NEMAW 10526721

// ---- MFMA path params
#define NCH          2                    // code chunks
#define CODES_PER_CH (K_CODES / NCH)      // 4096
#define NT_TILES     (CODES_PER_CH / 256) // 16

typedef __attribute__((ext_vector_type(8))) short short8;
typedef __attribute__((ext_vector_type(4))) float floatx4;

__device__ __forceinline__ unsigned short f2bf_rne(float x) {
    unsigned u = __float_as_uint(x);
    u += 0x7fffu + ((u >> 16) & 1u);
    return (unsigned short)(u >> 16);
}
__device__ __forceinline__ float bf2f(unsigned short h) {
    return __uint_as_float(((unsigned)h) << 16);
}
__device__ __forceinline__ void async16(const void* g, void* l) {
    __builtin_amdgcn_global_load_lds(
        (const __attribute__((address_space(1))) void*)g,
        (__attribute__((address_space(3))) void*)l, 16, 0, 0);
}

// ---------------------------------------------------------------- fused convert: z & emb -> {hi,lo} bf16 + |e|^2 + zero
__global__ void k_prep(const float* __restrict__ z, const float* __restrict__ emb,
                       unsigned short* __restrict__ zcat, unsigned short* __restrict__ ecat,
                       float* __restrict__ esq, int* __restrict__ zero16k) {
    const int b = blockIdx.x;
    if (b < 8192) {
        const int i = b * 256 + threadIdx.x;         // float4 idx, 2,097,152
        const int row = i >> 6;
        const int col = (i & 63) << 2;
        float4 v = ((const float4*)z)[i];
        // fold -2 into z: bf16(-2z) == -2*bf16(z) exactly (pow2 scale)
        float nx = -2.0f * v.x, ny = -2.0f * v.y, nz = -2.0f * v.z, nw = -2.0f * v.w;
        ushort4 h, l;
        h.x = f2bf_rne(nx); l.x = f2bf_rne(nx - bf2f(h.x));
        h.y = f2bf_rne(ny); l.y = f2bf_rne(ny - bf2f(h.y));
        h.z = f2bf_rne(nz); l.z = f2bf_rne(nz - bf2f(h.z));
        h.w = f2bf_rne(nw); l.w = f2bf_rne(nw - bf2f(h.w));
        *(ushort4*)&zcat[(size_t)row * 512 + col]       = h;
        *(ushort4*)&zcat[(size_t)row * 512 + 256 + col] = l;
    } else {
        const int gid  = (b - 8192) * 256 + threadIdx.x;  // 0..524287
        if (gid < 2 * K_CODES) zero16k[gid] = 0;          // counts + cursor
        const int code = gid >> 6;
        const int lane = gid & 63;
        const int col  = lane << 2;
        float4 v = ((const float4*)emb)[code * 64 + lane];
        ushort4 h, l;
        h.x = f2bf_rne(v.x); l.x = f2bf_rne(v.x - bf2f(h.x));
        h.y = f2bf_rne(v.y); l.y = f2bf_rne(v.y - bf2f(h.y));
        h.z = f2bf_rne(v.z); l.z = f2bf_rne(v.z - bf2f(h.z));
        h.w = f2bf_rne(v.w); l.w = f2bf_rne(v.w - bf2f(h.w));
        *(ushort4*)&ecat[(size_t)code * 512 + col]       = h;
        *(ushort4*)&ecat[(size_t)code * 512 + 256 + col] = l;
        float s = fmaf(v.x, v.x, fmaf(v.y, v.y, fmaf(v.z, v.z, v.w * v.w)));
#pragma unroll
        for (int off = 32; off > 0; off >>= 1) s += __shfl_down(s, off, 64);
        if (lane == 0) esq[code] = s;
    }
}

// ---------------------------------------------------------------- MFMA argmin GEMM (virtual K=768, BK=32, 128x256 tile)
// score(n,k) = esq[k] + dot(zcat_n, ecat_k segs), zcat encodes -2z.
// A segs {hi,hi,lo}: off_a=(k0&255)|((k0&512)>>1); B segs {hi,lo,hi}: off_b=k0&511.
// 2-phase double-buffered pipeline: stage step s+1 (global_load_lds into
// buf^1) issued BEFORE compute of step s (ds_read from buf); the single
// __syncthreads() per step drains the prefetch after it hid under 32 MFMAs.
// LDS layout (BK=32, 64B rows of 4x16B chunks): logical chunk c of row R at
// physical chunk c ^ ((R>>1)&3). Per aligned 8-lane phase group the b128
// reads cover 8 distinct 16B slots (even m -> banks 0-15, odd m -> 16-31):
// conflict-free (verified r6/r7: SQ_LDS_BANK_CONFLICT=0). Stage pre-swizzles
// the GLOBAL source (linear LDS dest, as global_load_lds requires).
// 4 waves, wave-tile 64x128: wrow=(w>>1)*64, wcol=(w&1)*128, acc 4x8 of 16x16x32.
#define STAGE(AS, BS, BGP, offa, offb)                                          \
    do {                                                                        \
        _Pragma("unroll")                                                       \
        for (int c_ = 0; c_ < 6; ++c_) {                                        \
            const int u_ = w * 6 + c_;                                          \
            if (u_ < 8)                                                         \
                async16(aGlob + (size_t)u_ * 8192 + (offa), &AS[u_ * 512]);     \
            else                                                                \
                async16((BGP) + (size_t)(u_ - 8) * 8192 + (offb),               \
                        &BS[(u_ - 8) * 512]);                                   \
        }                                                                       \
    } while (0)

// B fragments resident (32 VGPR), A streamed one at a time (4 VGPR):
// peak fragment live set 36 regs to stay under the 128-arch-VGPR budget.
#define COMPUTE(AS, BS)                                                         \
    do {                                                                        \
        short8 bf_[8];                                                          \
        _Pragma("unroll")                                                       \
        for (int j_ = 0; j_ < 8; ++j_)                                          \
            bf_[j_] = *(const short8*)&BS[(wcol + j_ * 16 + m) * 32 + xo];      \
        _Pragma("unroll")                                                       \
        for (int i_ = 0; i_ < 4; ++i_) {                                        \
            const short8 af_ =                                                  \
                *(const short8*)&AS[(wrow + i_ * 16 + m) * 32 + xo];            \
            _Pragma("unroll")                                                   \
            for (int j_ = 0; j_ < 8; ++j_)                                      \
                acc[i_][j_] = __builtin_amdgcn_mfma_f32_16x16x32_bf16(          \
                    af_, bf_[j_], acc[i_][j_], 0, 0, 0);                        \
        }                                                                       \
    } while (0)

__global__ __launch_bounds__(256, 2) void k_argmin_mfma(
        const unsigned short* __restrict__ zcat, const unsigned short* __restrict__ ecat,
        const float* __restrict__ esq,
        float* __restrict__ part_v, int* __restrict__ part_i) {
    // double buffer as SEPARATE arrays (alias analysis keeps stage/compute
    // independent). A: 128x32 ushort = 8 KB each; B: 256x32 = 16 KB each.
    __shared__ __align__(16) unsigned short a0_s[128 * 32];
    __shared__ __align__(16) unsigned short a1_s[128 * 32];
    __shared__ __align__(16) unsigned short b0_s[256 * 32];
    __shared__ __align__(16) unsigned short b1_s[256 * 32];
    const int t    = threadIdx.x;
    const int w    = t >> 6;
    const int lane = t & 63;
    const int quad = lane >> 4;
    const int m    = lane & 15;
    const int wrow = (w >> 1) * 64;
    const int wcol = (w & 1) * 128;
    const int row0   = blockIdx.x * 128;
    const int cbase0 = blockIdx.y * CODES_PER_CH;

    // staging geometry: 1536 16B slots/step (512 A + 1024 B) = 24 wave-chunks
    // of 64 slots; wave w takes u = w*6..w*6+5 (u<8 -> A rows u*16.., else B
    // rows (u-8)*16..). Lane covers slot (prow=lane>>2, pchunk=lane&3) which
    // holds logical chunk (lane&3) ^ ((lane>>3)&3) of its row.
    const int    swz    = (((lane & 3) ^ ((lane >> 3) & 3)) << 3);  // ushorts
    const size_t srcrow = (size_t)(lane >> 2) * 512 + swz;
    const unsigned short* aGlob = zcat + (size_t)row0 * 512 + srcrow;
    const unsigned short* bGlob = ecat + (size_t)cbase0 * 512 + srcrow;

    // fragment-read swizzle: physical chunk = quad ^ ((m>>1)&3), kk-invariant
    const int xo = ((quad ^ ((m >> 1) & 3)) << 3);

    float    best_v[16];
    unsigned best_p[4];     // per i: 4 reg-slots x 8-bit candidate (nt*8+j)
#pragma unroll
    for (int r = 0; r < 16; ++r) best_v[r] = FLT_MAX;
#pragma unroll
    for (int i = 0; i < 4; ++i) best_p[i] = 0u;

    // prologue: stage (nt=0, k0=0) into buf0
    STAGE(a0_s, b0_s, bGlob, 0, 0);
    __syncthreads();   // drains prologue stage (vmcnt 0 at barrier)

    for (int nt = 0; nt < NT_TILES; ++nt) {
        const int cb = cbase0 + nt * 256;
        const unsigned short* bNT  = bGlob + (size_t)nt * 131072;
        const unsigned short* bNT1 = bNT + 131072;
        floatx4 acc[4][8];
#pragma unroll
        for (int j = 0; j < 8; ++j) {
            const float es = esq[cb + wcol + j * 16 + m];
#pragma unroll
            for (int i = 0; i < 4; ++i) acc[i][j] = (floatx4){es, es, es, es};
        }

        // unroll 1: keep ONE copy of the two-step body so the compiler can't
        // hoist 12 iterations' worth of 64-bit staging addresses (the r6/r7
        // scratch-spill mechanism: WRITE_SIZE 271/181 MB).
#pragma unroll 1
        for (int kk2 = 0; kk2 < 12; ++kk2) {
            {   // step A: stage k0=64*kk2+32 into buf1, compute 64*kk2 from buf0
                const int nk0 = kk2 * 64 + 32;
                STAGE(a1_s, b1_s, bNT, (nk0 & 255) | ((nk0 & 512) >> 1), nk0 & 511);
                COMPUTE(a0_s, b0_s);
                __syncthreads();
            }
            {   // step B: stage next step into buf0, compute from buf1
                if (kk2 < 11) {
                    const int nk0 = kk2 * 64 + 64;
                    STAGE(a0_s, b0_s, bNT, (nk0 & 255) | ((nk0 & 512) >> 1), nk0 & 511);
                } else if (nt + 1 < NT_TILES) {
                    STAGE(a0_s, b0_s, bNT1, 0, 0);    // first step of next nt
                }
                COMPUTE(a1_s, b1_s);
                __syncthreads();
            }
        }
        // epilogue: acc IS the score. codes ascend in (nt,j): strict < = first-min.
#pragma unroll
        for (int j = 0; j < 8; ++j) {
            const unsigned cand = (unsigned)(nt * 8 + j);   // 7 bits
#pragma unroll
            for (int i = 0; i < 4; ++i)
#pragma unroll
                for (int reg = 0; reg < 4; ++reg) {
                    const float s = acc[i][j][reg];
                    const int r = i * 4 + reg;
                    if (s < best_v[r]) {
                        best_v[r] = s;
                        best_p[i] = (best_p[i] & ~(255u << (reg * 8))) | (cand << (reg * 8));
                    }
                }
        }
    }
    // reconstruct codes, butterfly across the 16 lanes sharing each row
    __syncthreads();               // staging LDS free for reuse
    float* redv = (float*)a0_s;    // [128][2]
    int*   redi = (int*)b0_s;      // [128][2]
#pragma unroll
    for (int i = 0; i < 4; ++i)
#pragma unroll
        for (int reg = 0; reg < 4; ++reg) {
            const int r = i * 4 + reg;
            const unsigned b = (best_p[i] >> (reg * 8)) & 255u;
            float v  = best_v[r];
            int   bi = cbase0 + (int)(b >> 3) * 256 + wcol + (int)(b & 7) * 16 + m;
#pragma unroll
            for (int off = 1; off < 16; off <<= 1) {
                const float ov = __shfl_xor(v, off, 64);
                const int   oi = __shfl_xor(bi, off, 64);
                if (ov < v || (ov == v && oi < bi)) { v = ov; bi = oi; }
            }
            if (m == 0) {
                const int row = wrow + i * 16 + quad * 4 + reg;
                redv[row * 2 + (w & 1)] = v;
                redi[row * 2 + (w & 1)] = bi;
            }
        }
    __syncthreads();
    if (t < 128) {
        const float v0 = redv[t * 2], v1 = redv[t * 2 + 1];
        const int   i0 = redi[t * 2], i1 = redi[t * 2 + 1];
        const bool  b1 = (v1 < v0) || (v1 == v0 && i1 < i0);
        const size_t o = (size_t)blockIdx.y * NROWS + blockIdx.x * 128 + t;
        part_v[o] = b1 ? v1 : v0;
        part_i[o] = b1 ? i1 : i0;
    }
}

#undef STAGE
#undef COMPUTE

// ---------------------------------------------------------------- merge partials + histogram
__global__ void k_reduce_part(const float* __restrict__ pv, const int* __restrict__ pi,
                              int* __restrict__ idx_i, float* __restrict__ idx_f,
                              int* __restrict__ counts) {
    const int r = blockIdx.x * blockDim.x + threadIdx.x;
    float v = pv[r]; int bi = pi[r];
#pragma unroll
    for (int c = 1; c < NCH; ++c) {
        const float v2 = pv[(size_t)c * NROWS + r];
        const int   i2 = pi[(size_t)c * NROWS + r];
        if (v2 < v || (v2 == v && i2 < bi)) { v = v2; bi = i2; }
    }
    idx_i[r] = bi;
    idx_f[r] = (float)bi;
    atomicAdd(&counts[bi], 1);
}

// ---------------------------------------------------------------- scan + new_cluster_size + n  (1 block, 1024 thr)
__global__ void k_scan_ncs(const int* __restrict__ counts, const float* __restrict__ ema_cs,
                           int* __restrict__ offsets, float* __restrict__ ncs_out,
                           float* __restrict__ ntot) {
    __shared__ int   wsum[16];
    __shared__ float red[16];
    const int t = threadIdx.x;
    const int lane = t & 63, w = t >> 6;
    int c[8]; int s = 0; float fs = 0.0f;
#pragma unroll
    for (int u = 0; u < 8; ++u) {
        c[u] = counts[t * 8 + u]; s += c[u];
        const float v = fmaf(0.99f, ema_cs[t * 8 + u], 0.01f * (float)c[u]);
        ncs_out[t * 8 + u] = v;
        fs += v;
    }
    int inc = s;
#pragma unroll
    for (int off = 1; off < 64; off <<= 1) {
        const int n = __shfl_up(inc, off, 64);
        if (lane >= off) inc += n;
    }
#pragma unroll
    for (int off = 32; off > 0; off >>= 1) fs += __shfl_down(fs, off, 64);
    if (lane == 63) wsum[w] = inc;
    if (lane == 0)  red[w]  = fs;
    __syncthreads();
    if (t < 16) {
        int v = wsum[t];
#pragma unroll
        for (int off = 1; off < 16; off <<= 1) {
            const int n = __shfl_up(v, off, 64);
            if (t >= off) v += n;
        }
        wsum[t] = v;
        float fv = red[t];
#pragma unroll
        for (int off = 8; off > 0; off >>= 1) fv += __shfl_down(fv, off, 16);
        if (t == 0) *ntot = fv;
    }
    __syncthreads();
    int base = (w > 0 ? wsum[w - 1] : 0) + (inc - s);
#pragma unroll
    for (int u = 0; u < 8; ++u) { offsets[t * 8 + u] = base; base += c[u]; }
}

// ---------------------------------------------------------------- zq + loss partials + bucket scatter
__global__ void k_zq(const float* __restrict__ z, const float* __restrict__ emb,
                     const int* __restrict__ idx_i, const int* __restrict__ offsets,
                     int* __restrict__ cursor, int* __restrict__ buckets,
                     float* __restrict__ zq, float* __restrict__ losspart) {
    __shared__ float lred[4];
    const int t = threadIdx.x;
    const int wr = t >> 6, lane = t & 63;
    const int row = blockIdx.x * 4 + wr;
    const int code = idx_i[row];
    float4 zv = ((const float4*)z)[row * 64 + lane];
    float4 ev = ((const float4*)emb)[(size_t)code * 64 + lane];
    float4 o = make_float4(zv.x + (ev.x - zv.x), zv.y + (ev.y - zv.y),
                           zv.z + (ev.z - zv.z), zv.w + (ev.w - zv.w));
    ((float4*)zq)[row * 64 + lane] = o;
    float dx = ev.x - zv.x, dy = ev.y - zv.y, dz = ev.z - zv.z, dw = ev.w - zv.w;
    float s = fmaf(dx, dx, fmaf(dy, dy, fmaf(dz, dz, dw * dw)));
#pragma unroll
    for (int off = 32; off > 0; off >>= 1) s += __shfl_down(s, off, 64);
    if (lane == 0) {
        lred[wr] = s;
        const int pos = atomicAdd(&cursor[code], 1);
        buckets[offsets[code] + pos] = row;
    }
    __syncthreads();
    if (t == 0) losspart[blockIdx.x] = (lred[0] + lred[1]) + (lred[2] + lred[3]);
}

// ---------------------------------------------------------------- dw + new_ema_w + new_embedding (+loss tail block)
__global__ void k_dw_nemb(const float* __restrict__ z, const float* __restrict__ ema_w,
                          const int* __restrict__ counts, const int* __restrict__ offsets,
                          const int* __restrict__ buckets, const float* __restrict__ ncs,
                          const float* __restrict__ ntot_p, const float* __restrict__ losspart,
                          float* __restrict__ nemaw, float* __restrict__ nemb,
                          float* __restrict__ loss_out) {
    __shared__ float lred[4];
    if (blockIdx.x == K_CODES) {          // loss finalize
        const int t = threadIdx.x;        // 256
        float s = 0.0f;
        for (int i = t; i < 8192; i += 256) s += losspart[i];
#pragma unroll
        for (int off = 32; off > 0; off >>= 1) s += __shfl_down(s, off, 64);
        if ((t & 63) == 0) lred[t >> 6] = s;
        __syncthreads();
        if (t == 0)
            *loss_out = 0.25f * ((lred[0] + lred[1]) + (lred[2] + lred[3])) / 8388608.0f;
        return;
    }
    const int code = blockIdx.x;
    const int d    = threadIdx.x;         // 256 = DIM
    const int cnt  = counts[code];
    const int off  = offsets[code];
    float acc = 0.0f;
    for (int it = 0; it < cnt; ++it)
        acc += z[(size_t)buckets[off + it] * DIM + d];
    const float wv = fmaf(0.99f, ema_w[(size_t)code * DIM + d], 0.01f * acc);
    nemaw[(size_t)code * DIM + d] = wv;
    const float n  = *ntot_p;
    const float cs = (ncs[code] + 1e-5f) * (n / (n + (float)K_CODES * 1e-5f));
    nemb[(size_t)code * DIM + d] = wv / cs;
}

// ================================================================ fp32 fallback path (round-1 verified)
#define BM   64
#define BN   128
#define LSTR 36

__global__ void k_esq_zero_fb(const float* __restrict__ emb, float* __restrict__ esq,
                              float* __restrict__ zbuf) {
    const int gid  = blockIdx.x * blockDim.x + threadIdx.x;
    if (gid < K_CODES + 2) zbuf[gid] = 0.0f;
    const int code = gid >> 6;
    const int lane = gid & 63;
    float4 v = ((const float4*)emb)[code * 64 + lane];
    float s = fmaf(v.x, v.x, fmaf(v.y, v.y, fmaf(v.z, v.z, v.w * v.w)));
#pragma unroll
    for (int off = 32; off > 0; off >>= 1) s += __shfl_down(s, off, 64);
    if (lane == 0) esq[code] = s;
}

__global__ void k_init_nemaw_fb(const float* __restrict__ ema_w, float* __restrict__ out) {
    const int i = blockIdx.x * blockDim.x + threadIdx.x;
    float4 v = ((const float4*)ema_w)[i];
    ((float4*)out)[i] = make_float4(0.99f * v.x, 0.99f * v.y, 0.99f * v.z, 0.99f * v.w);
}

__global__ __launch_bounds__(256, 2) void k_argmin_fb(
        const float* __restrict__ z, const float* __restrict__ emb,
        const float* __restrict__ esq, int* __restrict__ idx_i, float* __restrict__ idx_f) {
    __shared__ float z_s[BM * LSTR];
    __shared__ float e_s[BN * LSTR];
    const int t = threadIdx.x, tx = t & 15, ty = t >> 4;
    const int row0 = blockIdx.x * BM;
    float best[4]; int bidx[4];
#pragma unroll
    for (int r = 0; r < 4; ++r) { best[r] = FLT_MAX; bidx[r] = 0; }
    for (int k0 = 0; k0 < K_CODES; k0 += BN) {
        float acc[4][8];
#pragma unroll
        for (int r = 0; r < 4; ++r)
#pragma unroll
            for (int c = 0; c < 8; ++c) acc[r][c] = 0.0f;
        for (int d0 = 0; d0 < DIM; d0 += 32) {
            __syncthreads();
#pragma unroll
            for (int i = 0; i < 2; ++i) {
                int f = i * 256 + t, r = f >> 3, c4 = (f & 7) << 2;
                *(float4*)&z_s[r * LSTR + c4] =
                    *(const float4*)(z + (size_t)(row0 + r) * DIM + d0 + c4);
            }
#pragma unroll
            for (int i = 0; i < 4; ++i) {
                int f = i * 256 + t, c = f >> 3, c4 = (f & 7) << 2;
                *(float4*)&e_s[c * LSTR + c4] =
                    *(const float4*)(emb + (size_t)(k0 + c) * DIM + d0 + c4);
            }
            __syncthreads();
#pragma unroll
            for (int dd = 0; dd < 32; dd += 4) {
                float4 a[4], b[8];
#pragma unroll
                for (int j = 0; j < 4; ++j)
                    a[j] = *(const float4*)&z_s[(ty * 4 + j) * LSTR + dd];
#pragma unroll
                for (int j = 0; j < 8; ++j)
                    b[j] = *(const float4*)&e_s[(tx + 16 * j) * LSTR + dd];
#pragma unroll
                for (int r = 0; r < 4; ++r)
#pragma unroll
                    for (int c = 0; c < 8; ++c) {
                        acc[r][c] = fmaf(a[r].x, b[c].x, acc[r][c]);
                        acc[r][c] = fmaf(a[r].y, b[c].y, acc[r][c]);
                        acc[r][c] = fmaf(a[r].z, b[c].z, acc[r][c]);
                        acc[r][c] = fmaf(a[r].w, b[c].w, acc[r][c]);
                    }
            }
        }
#pragma unroll
        for (int c = 0; c < 8; ++c) {
            const int code = k0 + tx + 16 * c;
            const float es = esq[code];
#pragma unroll
            for (int r = 0; r < 4; ++r) {
                float s = fmaf(-2.0f, acc[r][c], es);
                if (s < best[r] || (s == best[r] && code < bidx[r])) {
                    best[r] = s; bidx[r] = code;
                }
            }
        }
    }
    __syncthreads();
    float* rv = e_s; int* ri = (int*)z_s;
#pragma unroll
    for (int r = 0; r < 4; ++r) {
        rv[(ty * 4 + r) * 16 + tx] = best[r];
        ri[(ty * 4 + r) * 16 + tx] = bidx[r];
    }
    __syncthreads();
    if (t < 64) {
        float mv = rv[t * 16]; int mi = ri[t * 16];
#pragma unroll
        for (int i = 1; i < 16; ++i) {
            float v = rv[t * 16 + i]; int vi = ri[t * 16 + i];
            if (v < mv || (v == mv && vi < mi)) { mv = v; mi = vi; }
        }
        idx_i[row0 + t] = mi;
        idx_f[row0 + t] = (float)mi;
    }
}

__global__ void k_gather_fb(const float* __restrict__ z, const float* __restrict__ emb,
                            const int* __restrict__ idx_i, float* __restrict__ zq,
                            float* __restrict__ nemaw, float* __restrict__ counts,
                            float* __restrict__ loss) {
    const int gid  = blockIdx.x * blockDim.x + threadIdx.x;
    const int row  = gid >> 6;
    const int lane = gid & 63;
    const int code = idx_i[row];
    float4 zv = ((const float4*)z)[row * 64 + lane];
    float4 ev = ((const float4*)emb)[(size_t)code * 64 + lane];
    float4 o = make_float4(zv.x + (ev.x - zv.x), zv.y + (ev.y - zv.y),
                           zv.z + (ev.z - zv.z), zv.w + (ev.w - zv.w));
    ((float4*)zq)[row * 64 + lane] = o;
    float dx = ev.x - zv.x, dy = ev.y - zv.y, dz = ev.z - zv.z, dw = ev.w - zv.w;
    float s = fmaf(dx, dx, fmaf(dy, dy, fmaf(dz, dz, dw * dw)));
#pragma unroll
    for (int off = 32; off > 0; off >>= 1) s += __shfl_down(s, off, 64);
    if (lane == 0) { atomicAdd(loss, s); atomicAdd(&counts[code], 1.0f); }
    float* base = nemaw + (size_t)code * DIM + lane * 4;
    atomicAdd(base + 0, 0.01f * zv.x);
    atomicAdd(base + 1, 0.01f * zv.y);
    atomicAdd(base + 2, 0.01f * zv.z);
    atomicAdd(base + 3, 0.01f * zv.w);
}

__global__ void k_ncs_fb(const float* __restrict__ ema_cs, const float* __restrict__ counts,
                         float* __restrict__ ncs_out, float* __restrict__ ntot,
                         const float* __restrict__ loss_in, float* __restrict__ loss_out) {
    __shared__ float red[16];
    const int t = threadIdx.x;
    float s = 0.0f;
    for (int i = t; i < K_CODES; i += 1024) {
        float v = fmaf(0.99f, ema_cs[i], 0.01f * counts[i]);
        ncs_out[i] = v; s += v;
    }
#pragma unroll
    for (int off = 32; off > 0; off >>= 1) s += __shfl_down(s, off, 64);
    if ((t & 63) == 0) red[t >> 6] = s;
    __syncthreads();
    if (t < 16) {
        float v = red[t];
#pragma unroll
        for (int off = 8; off > 0; off >>= 1) v += __shfl_down(v, off, 16);
        if (t == 0) { *ntot = v; *loss_out = 0.25f * (*loss_in) / 8388608.0f; }
    }
}

__global__ void k_nemb_fb(const float* __restrict__ nemaw, const float* __restrict__ ncs,
                          const float* __restrict__ ntot_p, float* __restrict__ nemb) {
    const int i4 = blockIdx.x * blockDim.x + threadIdx.x;
    const int k  = i4 >> 6;
    const float n   = *ntot_p;
    const float inv = n / (n + (float)K_CODES * 1e-5f);
    const float cs  = (ncs[k] + 1e-5f) * inv;
    float4 wv = ((const float4*)nemaw)[i4];
    ((float4*)nemb)[i4] = make_float4(wv.x / cs, wv.y / cs, wv.z / cs, wv.w / cs);
}

extern "C" void kernel_launch(void* const* d_in, const int* in_sizes, int n_in,
                              void* d_out, int out_size, void* d_ws, size_t ws_size,
                              hipStream_t stream) {
    const float* z      = (const float*)d_in[0];
    const float* emb    = (const float*)d_in[1];
    const float* ema_cs = (const float*)d_in[2];
    const float* ema_w  = (const float*)d_in[3];
    float* out = (float*)d_out;
    char* wsb = (char*)d_ws;

    // ---- MFMA-path workspace layout (bytes), total 43,417,616 (NCH=2 uses
    // only half of part_v/part_i but offsets kept from r3 layout)
    unsigned short* zcat    = (unsigned short*)wsb;                  // 33,554,432
    unsigned short* ecat    = (unsigned short*)(wsb + 33554432);     //  8,388,608
    float*          part_v  = (float*)(wsb + 41943040);              //    524,288
    int*            part_i  = (int*)  (wsb + 42467328);              //    524,288
    float*          esq     = (float*)(wsb + 42991616);              //     32,768
    int*            ws_idx  = (int*)  (wsb + 43024384);              //    131,072
    int*            counts  = (int*)  (wsb + 43155456);              //     32,768
    int*            cursor  = (int*)  (wsb + 43188224);              //     32,768 (contiguous w/ counts)
    int*            offsets = (int*)  (wsb + 43220992);              //     32,768
    int*            buckets = (int*)  (wsb + 43253760);              //    131,072
    float*          lpart   = (float*)(wsb + 43384832);              //     32,768
    float*          ws_loss = (float*)(wsb + 43417600);
    float*          ws_ntot = ws_loss + 1;

    if (ws_size >= (size_t)43417616) {
        k_prep       <<<10240, 256, 0, stream>>>(z, emb, zcat, ecat, esq, counts);
        k_argmin_mfma<<<dim3(NROWS / 128, NCH), 256, 0, stream>>>(
            zcat, ecat, esq, part_v, part_i);
        k_reduce_part<<<NROWS / 256, 256, 0, stream>>>(part_v, part_i, ws_idx,
                                                       out + O_IDX, counts);
        k_scan_ncs   <<<1, 1024, 0, stream>>>(counts, ema_cs, offsets,
                                              out + O_NCS, ws_ntot);
        k_zq         <<<NROWS / 4, 256, 0, stream>>>(z, emb, ws_idx, offsets, cursor,
                                                     buckets, out + O_ZQ, lpart);
        k_dw_nemb    <<<K_CODES + 1, 256, 0, stream>>>(z, ema_w, counts, offsets, buckets,
                                                       out + O_NCS, ws_ntot, lpart,
                                                       out + O_NEMAW, out + O_NEMB,
                                                       out + O_LOSS);
    } else {
        // small-ws fallback (round-1 verified fp32 path)
        int*   f_idx    = (int*)wsb;
        float* f_counts = (float*)(wsb + 131072);
        float* f_loss   = f_counts + K_CODES;
        float* f_ntot   = f_loss + 1;
        float* f_esq    = (float*)(wsb + 163856);
        k_esq_zero_fb  <<<2048, 256, 0, stream>>>(emb, f_esq, f_counts);
        k_init_nemaw_fb<<<2048, 256, 0, stream>>>(ema_w, out + O_NEMAW);
        k_argmin_fb    <<<NROWS / BM, 256, 0, stream>>>(z, emb, f_esq, f_idx, out + O_IDX);
        k_gather_fb    <<<NROWS / 4, 256, 0, stream>>>(z, emb, f_idx, out + O_ZQ,
                                                       out + O_NEMAW, f_counts, f_loss);
        k_ncs_fb       <<<1, 1024, 0, stream>>>(ema_cs, f_counts, out + O_NCS, f_ntot,
                                                f_loss, out + O_LOSS);
        k_nemb_fb      <<<2048, 256, 0, stream>>>(out + O_NEMAW, out + O_NCS, f_ntot,
                                                  out + O_NEMB);
    }
}